// Round 3
// baseline (14453.825 us; speedup 1.0000x reference)
//
#include <hip/hip_runtime.h>

#define B_    64
#define S_    1024
#define H_    512
#define KTOT  1024              // I + H
#define BH    (B_ * H_)         // 32768 elements per h-state buffer
#define NWG   64                // 32 WGs per layer

typedef short        v8s __attribute__((ext_vector_type(8)));
typedef float        v4f __attribute__((ext_vector_type(4)));
typedef unsigned int v2u __attribute__((ext_vector_type(2)));

// Device-coherent (bypass L1+L2, IF$-visible) accesses for cross-WG h exchange.
#define GLOAD16(dst, p) asm volatile("global_load_dwordx4 %0, %1, off sc0 sc1" \
    : "=&v"(dst) : "v"((unsigned long long)(const void*)(p)) : "memory")
#define GSTORE8(p, v)   asm volatile("global_store_dwordx2 %0, %1, off sc0 sc1" \
    :: "v"((unsigned long long)(void*)(p)), "v"(v) : "memory")
// coherent 4B flag ops; load embeds its own drain (result needed immediately)
#define GLOADU32(dst, p) asm volatile("global_load_dword %0, %1, off sc0 sc1\n\ts_waitcnt vmcnt(0)" \
    : "=&v"(dst) : "v"((unsigned long long)(const void*)(p)) : "memory")
#define GSTOREU32(p, v) asm volatile("global_store_dword %0, %1, off sc0 sc1" \
    :: "v"((unsigned long long)(void*)(p)), "v"(v) : "memory")
#define VMWAIT(n)       asm volatile("s_waitcnt vmcnt(" #n ")" ::: "memory")

__device__ __forceinline__ unsigned short f2b_rne(float f) {   // exact round-nearest-even
    union { float f; unsigned int i; } c; c.f = f;
    unsigned int x = c.i;
    return (unsigned short)((x + 0x7fffu + ((x >> 16) & 1u)) >> 16);
}

// pack two fp32 -> bf16x2 dword (round-half-up via +0x8000, then byte-perm)
__device__ __forceinline__ unsigned rnpack(float a, float b) {
    union { float f; unsigned u; } x, y; x.f = a; y.f = b;
    return __builtin_amdgcn_perm(y.u + 0x8000u, x.u + 0x8000u, 0x07060302u);
}

union frag_u { v8s s; unsigned u[4]; };

__device__ __forceinline__ v8s pack8(const float4 f0, const float4 f1) {
    frag_u r;
    r.u[0] = rnpack(f0.x, f0.y);
    r.u[1] = rnpack(f0.z, f0.w);
    r.u[2] = rnpack(f1.x, f1.y);
    r.u[3] = rnpack(f1.z, f1.w);
    return r.s;
}

// LDS layout for transposed weight slice: column n in [0,16), k in [0,1024).
// XOR-octet swizzle: no pad bytes, 16B-aligned frag reads, 2-way max conflict (free).
__device__ __forceinline__ int bidx(int n, int k) {
    int k8 = k >> 3;
    return (n << 10) + (((k8 ^ (n & 7)) << 3) | (k & 7));
}

__global__ __launch_bounds__(256, 1) void gru_fused(
    const float* __restrict__ Xin,   // (B, S, 512) fp32
    const float* __restrict__ Wg,    // (2, 1024, 512)
    const float* __restrict__ bgp,   // (2, 512)
    const float* __restrict__ Wi,    // (2, 512, 512)
    const float* __restrict__ bip,   // (2, 512)
    const float* __restrict__ Wh,    // (2, 512, 512)
    float* __restrict__ Yout,        // (B, S, 512) final-layer output
    float* __restrict__ hfin,        // (2, B, 512) final hidden (fp32)
    unsigned short* __restrict__ h0buf, // 2 parities x (B,512) bf16 layer-0 h
    unsigned short* __restrict__ h1buf, // 2 parities x (B,512) bf16 layer-1 h
    unsigned int* __restrict__ flags)   // 64 CONTIGUOUS u32 phase flags (2 cachelines)
{
    __shared__ unsigned short Bz[16 * KTOT];  // 32 KB  [Wgx; Wgh] cols n0..n0+15, transposed, bf16
    __shared__ unsigned short Bc[16 * KTOT];  // 32 KB  [Wi ; Wh ] cols, transposed, bf16

    const int tid   = threadIdx.x;
    const int layer = blockIdx.x >> 5;        // 0 or 1
    const int n0    = (blockIdx.x & 31) * 16; // column group

    const float* Wgs = Wg + (size_t)layer * KTOT * 512;
    const float* Wis = Wi + (size_t)layer * 512 * 512;
    const float* Whs = Wh + (size_t)layer * 512 * 512;

    // one-time: transpose + RNE-quantize + swizzle weight slices into LDS
    for (int idx = tid; idx < 16 * KTOT; idx += 256) {
        int n = idx & 15;
        int k = idx >> 4;
        Bz[bidx(n, k)] = f2b_rne(Wgs[k * 512 + n0 + n]);
        Bc[bidx(n, k)] = f2b_rne((k < 512) ? Wis[k * 512 + n0 + n]
                                           : Whs[(k - 512) * 512 + n0 + n]);
    }
    __syncthreads();

    const int wave = tid >> 6;
    const int lane = tid & 63;
    const int mloc = lane & 15;
    const int quad = lane >> 4;

    // OPERAND-SWAPPED MFMA: a = W frag (A row = weight col = mloc),
    //                       b = xh frag (B col = batch row = arow).
    // D: col = lane&15 -> batch row arow; row = quad*4+i -> weight col ncol+i.
    // => each lane owns 1 batch row x 4 CONTIGUOUS H columns: wide stores.
    const int arow = wave * 16 + mloc;        // batch row this lane owns
    const int ncol = n0 + (quad << 2);        // first of its 4 H columns

    const v4f bg4 = *(const v4f*)(bgp + layer * 512 + ncol);
    const v4f bi4 = *(const v4f*)(bip + layer * 512 + ncol);

    unsigned short* myh = (layer == 0) ? h0buf : h1buf;

    float hreg[4] = {0.f, 0.f, 0.f, 0.f};     // own h entries, full fp32

    const int lds_off = mloc << 10;
    const int swz = mloc & 7;

    v8s xa[16];                                // x-operand frags (held across barrier for L0)
    if (layer == 0) {                          // prefetch+pack X(t=0)
        const float* xp = Xin + (size_t)arow * S_ * 512 + (quad << 3);
        #pragma unroll
        for (int kk = 0; kk < 16; ++kk) {
            float4 f0 = *(const float4*)(xp + kk * 32);
            float4 f1 = *(const float4*)(xp + kk * 32 + 4);
            xa[kk] = pack8(f0, f1);
        }
    }

    // pipelined phases: layer 0 computes t=p, layer 1 computes t=p-1
    for (int p = 0; p <= S_; ++p) {
        const int t = (layer == 0) ? p : (p - 1);
        if (t >= 0 && t < S_) {
            v8s ha[16];
            const unsigned short* hsrc = myh + (t & 1) * BH + arow * 512 + (quad << 3);
            if (layer == 1) {
                // x source for L1: h0 "after step t" = parity (t+1)&1, bf16, coherent
                const unsigned short* xsrc = h0buf + ((t + 1) & 1) * BH + arow * 512 + (quad << 3);
                #pragma unroll
                for (int kk = 0; kk < 16; ++kk) GLOAD16(xa[kk], xsrc + kk * 32);
            }
            #pragma unroll
            for (int kk = 0; kk < 16; ++kk) GLOAD16(ha[kk], hsrc + kk * 32);

            v4f az0 = {0.f,0.f,0.f,0.f}, az1 = {0.f,0.f,0.f,0.f};
            v4f ac0 = {0.f,0.f,0.f,0.f}, ac1 = {0.f,0.f,0.f,0.f};

            if (layer == 1) { VMWAIT(16); __builtin_amdgcn_sched_barrier(0); }

            // x-part MFMAs: L0 uses prefetched regs (h-load latency hides under these);
            // L1 waited only for its first 16 loads (counted vmcnt).
            #pragma unroll
            for (int kk = 0; kk < 16; ++kk) {
                int k8 = (kk * 4 + quad) ^ swz;
                v8s bz = *(const v8s*)(&Bz[lds_off + (k8 << 3)]);
                v8s bc = *(const v8s*)(&Bc[lds_off + (k8 << 3)]);
                if (kk & 1) {
                    az1 = __builtin_amdgcn_mfma_f32_16x16x32_bf16(bz, xa[kk], az1, 0, 0, 0);
                    ac1 = __builtin_amdgcn_mfma_f32_16x16x32_bf16(bc, xa[kk], ac1, 0, 0, 0);
                } else {
                    az0 = __builtin_amdgcn_mfma_f32_16x16x32_bf16(bz, xa[kk], az0, 0, 0, 0);
                    ac0 = __builtin_amdgcn_mfma_f32_16x16x32_bf16(bc, xa[kk], ac0, 0, 0, 0);
                }
            }

            VMWAIT(0); __builtin_amdgcn_sched_barrier(0);

            // issue next-step X prefetch NOW (after the counted waits, before h-MFMAs):
            // its latency hides under h-MFMAs + epilogue.
            if (layer == 0 && t + 1 < S_) {
                const float* xp = Xin + ((size_t)arow * S_ + (t + 1)) * 512 + (quad << 3);
                #pragma unroll
                for (int kk = 0; kk < 16; ++kk) {
                    float4 f0 = *(const float4*)(xp + kk * 32);
                    float4 f1 = *(const float4*)(xp + kk * 32 + 4);
                    xa[kk] = pack8(f0, f1);
                }
            }

            #pragma unroll
            for (int kk = 0; kk < 16; ++kk) {
                int k8 = ((kk + 16) * 4 + quad) ^ swz;
                v8s bz = *(const v8s*)(&Bz[lds_off + (k8 << 3)]);
                v8s bc = *(const v8s*)(&Bc[lds_off + (k8 << 3)]);
                if (kk & 1) {
                    az1 = __builtin_amdgcn_mfma_f32_16x16x32_bf16(bz, ha[kk], az1, 0, 0, 0);
                    ac1 = __builtin_amdgcn_mfma_f32_16x16x32_bf16(bc, ha[kk], ac1, 0, 0, 0);
                } else {
                    az0 = __builtin_amdgcn_mfma_f32_16x16x32_bf16(bz, ha[kk], az0, 0, 0, 0);
                    ac0 = __builtin_amdgcn_mfma_f32_16x16x32_bf16(bc, ha[kk], ac0, 0, 0, 0);
                }
            }

            v4f az = az0 + az1;
            v4f ac = ac0 + ac1;

            unsigned short* hd = myh + ((t + 1) & 1) * BH;

            #pragma unroll
            for (int i = 0; i < 4; ++i) {
                float zp = az[i] + bg4[i];
                float cp = ac[i] + bi4[i];
                zp = fminf(fmaxf(zp, -30.f), 30.f);
                cp = fminf(fmaxf(cp, -15.f), 15.f);
                float z  = 1.f / (1.f + __expf(-zp));
                float e  = __expf(2.f * cp);
                float cc = (e - 1.f) / (e + 1.f);
                hreg[i] = (1.f - z) * hreg[i] + z * cc;
            }

            // one 8B coherent store: 4 contiguous bf16 h values (row arow, cols ncol..+3)
            v2u hp2;
            hp2[0] = rnpack(hreg[0], hreg[1]);
            hp2[1] = rnpack(hreg[2], hreg[3]);
            GSTORE8(hd + arow * 512 + ncol, hp2);

            if (layer == 1) {
                v4f hv = {hreg[0], hreg[1], hreg[2], hreg[3]};
                *(v4f*)(Yout + ((size_t)arow * S_ + t) * 512 + ncol) = hv;
            }
        }

        if (p == S_) break;   // last phase needs no trailing barrier

        // ---- distributed flag barrier (COALESCED) ------------------------
        // Release: drain own vm ops (h store at coherence point), s_barrier,
        // then lane 0 posts the phase number to this WG's PRIVATE u32 flag.
        // Flags are CONTIGUOUS (64 x u32 = 256 B = 2 cachelines): the poll is
        // a fully-coalesced wave load (2 transactions per round), not a
        // 64-line gather. Stores are posted writes into 2 lines — serialized
        // at the coherence point but fire-and-forget, off the critical path.
        VMWAIT(0);
        __syncthreads();
        {
            const unsigned tgt = (unsigned)(p + 1);
            if (wave == 0) {
                if (lane == 0) GSTOREU32(flags + blockIdx.x, tgt);
                const unsigned* fp = flags + lane;
                unsigned v;
                do { GLOADU32(v, fp); } while (__any(v < tgt));
            }
            __syncthreads();
        }
    }

    {
        v4f hv = {hreg[0], hreg[1], hreg[2], hreg[3]};
        *(v4f*)(hfin + (size_t)layer * BH + arow * 512 + ncol) = hv;
    }
}

extern "C" void kernel_launch(void* const* d_in, const int* in_sizes, int n_in,
                              void* d_out, int out_size, void* d_ws, size_t ws_size,
                              hipStream_t stream)
{
    const float* x  = (const float*)d_in[0];
    const float* Wg = (const float*)d_in[1];
    const float* bg = (const float*)d_in[2];
    const float* bi = (const float*)d_in[4];
    const float* Wi = (const float*)d_in[3];
    const float* Wh = (const float*)d_in[5];

    float* out = (float*)d_out;                       // (B,S,H)
    float* hid = out + (size_t)B_ * S_ * H_;          // (L,B,H)

    // ws layout (bytes): [h0 bf16 dbuf: 128KB][h1 bf16 dbuf: 128KB][flags: 64*4B]
    unsigned short* h0b = (unsigned short*)d_ws;
    unsigned short* h1b = h0b + 2 * BH;
    unsigned int*   flg = (unsigned int*)((char*)d_ws + (size_t)8 * BH);  // byte 262144

    hipMemsetAsync(d_ws, 0, (size_t)8 * BH + 4096, stream);   // h state + flags

    gru_fused<<<dim3(NWG), dim3(256), 0, stream>>>(
        x, Wg, bg, Wi, bi, Wh, out, hid, h0b, h1b, flg);
}

// Round 4
// 7433.878 us; speedup vs baseline: 1.9443x; 1.9443x over previous
//
#include <hip/hip_runtime.h>

#define B_    64
#define S_    1024
#define H_    512
#define KTOT  1024              // I + H
#define BH    32768             // shorts per parity per layer (64 rows * 512 cols)
#define NWG   64                // 32 WGs per layer

typedef short        v8s __attribute__((ext_vector_type(8)));
typedef float        v4f __attribute__((ext_vector_type(4)));
typedef unsigned int v2u __attribute__((ext_vector_type(2)));

// Device-coherent (bypass L1+L2, IF$-visible) accesses for cross-WG h exchange.
#define GLOAD16(dst, p) asm volatile("global_load_dwordx4 %0, %1, off sc0 sc1" \
    : "=&v"(dst) : "v"((unsigned long long)(const void*)(p)) : "memory")
#define GSTORE8(p, v)   asm volatile("global_store_dwordx2 %0, %1, off sc0 sc1" \
    :: "v"((unsigned long long)(void*)(p)), "v"(v) : "memory")
// coherent 4B flag ops; load embeds its own drain (result needed immediately)
#define GLOADU32(dst, p) asm volatile("global_load_dword %0, %1, off sc0 sc1\n\ts_waitcnt vmcnt(0)" \
    : "=&v"(dst) : "v"((unsigned long long)(const void*)(p)) : "memory")
#define GSTOREU32(p, v) asm volatile("global_store_dword %0, %1, off sc0 sc1" \
    :: "v"((unsigned long long)(void*)(p)), "v"(v) : "memory")
#define VMWAIT(n)       asm volatile("s_waitcnt vmcnt(" #n ")" ::: "memory")

__device__ __forceinline__ unsigned short f2b_rne(float f) {   // exact round-nearest-even
    union { float f; unsigned int i; } c; c.f = f;
    unsigned int x = c.i;
    return (unsigned short)((x + 0x7fffu + ((x >> 16) & 1u)) >> 16);
}

// pack two fp32 -> bf16x2 dword (round-half-up via +0x8000, then byte-perm)
__device__ __forceinline__ unsigned rnpack(float a, float b) {
    union { float f; unsigned u; } x, y; x.f = a; y.f = b;
    return __builtin_amdgcn_perm(y.u + 0x8000u, x.u + 0x8000u, 0x07060302u);
}

union frag_u { v8s s; unsigned u[4]; };

__device__ __forceinline__ v8s pack8(const float4 f0, const float4 f1) {
    frag_u r;
    r.u[0] = rnpack(f0.x, f0.y);
    r.u[1] = rnpack(f0.z, f0.w);
    r.u[2] = rnpack(f1.x, f1.y);
    r.u[3] = rnpack(f1.z, f1.w);
    return r.s;
}

// LDS layout for transposed weight slice: column n in [0,16), k in [0,1024).
// XOR-octet swizzle: no pad bytes, 16B-aligned frag reads, 2-way max conflict (free).
__device__ __forceinline__ int bidx(int n, int k) {
    int k8 = k >> 3;
    return (n << 10) + (((k8 ^ (n & 7)) << 3) | (k & 7));
}

// h-state storage is in MFMA B-FRAGMENT ORDER (the round-3 key change):
//   Hs[parity][wave:4][kk:16][lane:64][j:8] bf16,
//   element = h[wave*16 + (lane&15)][kk*32 + (lane>>4)*8 + j]
// Consumer: lane L loads 16B at (wave*8192 + kk*512 + L*8) shorts -> 64 lanes
// read 1KB CONTIGUOUS per instruction (was: 16 scattered 64B lines/instr).
// Producer: each lane's 4 owned cols are 4 consecutive j -> one coalesced 8B
// store; a wave's 64 stores cover 512B contiguous.

__global__ __launch_bounds__(256, 1) void gru_fused(
    const float* __restrict__ Xin,   // (B, S, 512) fp32
    const float* __restrict__ Wg,    // (2, 1024, 512)
    const float* __restrict__ bgp,   // (2, 512)
    const float* __restrict__ Wi,    // (2, 512, 512)
    const float* __restrict__ bip,   // (2, 512)
    const float* __restrict__ Wh,    // (2, 512, 512)
    float* __restrict__ Yout,        // (B, S, 512) final-layer output
    float* __restrict__ hfin,        // (2, B, 512) final hidden (fp32)
    unsigned short* __restrict__ h0s,   // 2 parities x 64KB layer-0 h (fragment order)
    unsigned short* __restrict__ h1s,   // 2 parities x 64KB layer-1 h (fragment order)
    unsigned int* __restrict__ flags)   // [0..63]: per-WG phase flags; [128]: epoch
{
    __shared__ unsigned short Bz[16 * KTOT];  // 32 KB  [Wgx; Wgh] cols n0..n0+15, transposed, bf16
    __shared__ unsigned short Bc[16 * KTOT];  // 32 KB  [Wi ; Wh ] cols, transposed, bf16

    const int tid   = threadIdx.x;
    const int layer = blockIdx.x >> 5;        // 0 or 1
    const int n0    = (blockIdx.x & 31) * 16; // column group

    const float* Wgs = Wg + (size_t)layer * KTOT * 512;
    const float* Wis = Wi + (size_t)layer * 512 * 512;
    const float* Whs = Wh + (size_t)layer * 512 * 512;

    // one-time: transpose + RNE-quantize + swizzle weight slices into LDS
    for (int idx = tid; idx < 16 * KTOT; idx += 256) {
        int n = idx & 15;
        int k = idx >> 4;
        Bz[bidx(n, k)] = f2b_rne(Wgs[k * 512 + n0 + n]);
        Bc[bidx(n, k)] = f2b_rne((k < 512) ? Wis[k * 512 + n0 + n]
                                           : Whs[(k - 512) * 512 + n0 + n]);
    }
    __syncthreads();

    const int wave = tid >> 6;
    const int lane = tid & 63;
    const int mloc = lane & 15;
    const int quad = lane >> 4;

    // OPERAND-SWAPPED MFMA: a = W frag (A row = weight col = mloc),
    //                       b = xh frag (B col = batch row = arow).
    // D: col = lane&15 -> batch row arow; row = quad*4+i -> weight col ncol+i.
    const int arow = wave * 16 + mloc;        // batch row this lane owns
    const int ncol = n0 + (quad << 2);        // first of its 4 H columns

    const v4f bg4 = *(const v4f*)(bgp + layer * 512 + ncol);
    const v4f bi4 = *(const v4f*)(bip + layer * 512 + ncol);

    unsigned short* myh = (layer == 0) ? h0s : h1s;

    // producer-side fragment-order offset for this lane's 4 h values
    const int sub   = ncol & 31;
    const int kk0   = ncol >> 5;
    const int lanep = ((sub >> 3) << 4) + mloc;   // lane' in fragment order
    const int j0    = sub & 7;                    // 0 or 4
    const int hoff  = wave * 8192 + kk0 * 512 + lanep * 8 + j0;   // shorts

    // consumer-side base (shorts): wave*8192 + lane*8, + kk*512 per tile
    const int coff  = wave * 8192 + lane * 8;

    float hreg[4] = {0.f, 0.f, 0.f, 0.f};     // own h entries, full fp32

    const int lds_off = mloc << 10;
    const int swz = mloc & 7;

    v8s xa[16];                                // x-operand frags (held across barrier for L0)
    if (layer == 0) {                          // prefetch+pack X(t=0)
        const float* xp = Xin + (size_t)arow * S_ * 512 + (quad << 3);
        #pragma unroll
        for (int kk = 0; kk < 16; ++kk) {
            float4 f0 = *(const float4*)(xp + kk * 32);
            float4 f1 = *(const float4*)(xp + kk * 32 + 4);
            xa[kk] = pack8(f0, f1);
        }
    }

    // pipelined phases: layer 0 computes t=p, layer 1 computes t=p-1
    for (int p = 0; p <= S_; ++p) {
        const int t = (layer == 0) ? p : (p - 1);
        if (t >= 0 && t < S_) {
            v8s ha[16];
            const unsigned short* hsrc = myh + (t & 1) * BH + coff;
            if (layer == 1) {
                // x source for L1: h0 "after step t" = parity (t+1)&1, fragment order
                const unsigned short* xsrc = h0s + ((t + 1) & 1) * BH + coff;
                #pragma unroll
                for (int kk = 0; kk < 16; ++kk) GLOAD16(xa[kk], xsrc + kk * 512);
            }
            #pragma unroll
            for (int kk = 0; kk < 16; ++kk) GLOAD16(ha[kk], hsrc + kk * 512);

            v4f az0 = {0.f,0.f,0.f,0.f}, az1 = {0.f,0.f,0.f,0.f};
            v4f ac0 = {0.f,0.f,0.f,0.f}, ac1 = {0.f,0.f,0.f,0.f};

            if (layer == 1) { VMWAIT(16); __builtin_amdgcn_sched_barrier(0); }

            // x-part MFMAs: L0 uses prefetched regs (h-load latency hides under these);
            // L1 waited only for its first 16 loads (counted vmcnt).
            #pragma unroll
            for (int kk = 0; kk < 16; ++kk) {
                int k8 = (kk * 4 + quad) ^ swz;
                v8s bz = *(const v8s*)(&Bz[lds_off + (k8 << 3)]);
                v8s bc = *(const v8s*)(&Bc[lds_off + (k8 << 3)]);
                if (kk & 1) {
                    az1 = __builtin_amdgcn_mfma_f32_16x16x32_bf16(bz, xa[kk], az1, 0, 0, 0);
                    ac1 = __builtin_amdgcn_mfma_f32_16x16x32_bf16(bc, xa[kk], ac1, 0, 0, 0);
                } else {
                    az0 = __builtin_amdgcn_mfma_f32_16x16x32_bf16(bz, xa[kk], az0, 0, 0, 0);
                    ac0 = __builtin_amdgcn_mfma_f32_16x16x32_bf16(bc, xa[kk], ac0, 0, 0, 0);
                }
            }

            VMWAIT(0); __builtin_amdgcn_sched_barrier(0);

            #pragma unroll
            for (int kk = 0; kk < 16; ++kk) {
                int k8 = ((kk + 16) * 4 + quad) ^ swz;
                v8s bz = *(const v8s*)(&Bz[lds_off + (k8 << 3)]);
                v8s bc = *(const v8s*)(&Bc[lds_off + (k8 << 3)]);
                if (kk & 1) {
                    az1 = __builtin_amdgcn_mfma_f32_16x16x32_bf16(bz, ha[kk], az1, 0, 0, 0);
                    ac1 = __builtin_amdgcn_mfma_f32_16x16x32_bf16(bc, ha[kk], ac1, 0, 0, 0);
                } else {
                    az0 = __builtin_amdgcn_mfma_f32_16x16x32_bf16(bz, ha[kk], az0, 0, 0, 0);
                    ac0 = __builtin_amdgcn_mfma_f32_16x16x32_bf16(bc, ha[kk], ac0, 0, 0, 0);
                }
            }

            v4f az = az0 + az1;
            v4f ac = ac0 + ac1;

            #pragma unroll
            for (int i = 0; i < 4; ++i) {
                float zp = az[i] + bg4[i];
                float cp = ac[i] + bi4[i];
                zp = fminf(fmaxf(zp, -30.f), 30.f);
                cp = fminf(fmaxf(cp, -15.f), 15.f);
                float z  = 1.f / (1.f + __expf(-zp));
                float e  = __expf(2.f * cp);
                float cc = (e - 1.f) / (e + 1.f);
                hreg[i] = (1.f - z) * hreg[i] + z * cc;
            }

            // one coalesced 8B coherent store into fragment-order h buffer
            v2u hp2;
            hp2[0] = rnpack(hreg[0], hreg[1]);
            hp2[1] = rnpack(hreg[2], hreg[3]);
            GSTORE8(myh + ((t + 1) & 1) * BH + hoff, hp2);

            if (layer == 1) {
                v4f hv = {hreg[0], hreg[1], hreg[2], hreg[3]};
                *(v4f*)(Yout + ((size_t)arow * S_ + t) * 512 + ncol) = hv;
            }
        }

        if (p == S_) break;   // last phase needs no trailing barrier

        // ---- two-level flag/epoch barrier --------------------------------
        // Release: drain own vm ops (h store at coherence point), s_barrier,
        // lane 0 posts the phase number to this WG's flag (contiguous array;
        // posted store, off critical path).
        // Aggregation: ONLY WG0/wave0 polls the 64 flags (one coalesced
        // 2-line load per round), then publishes epoch on its own line.
        // Acquire: other WGs poll the single read-mostly epoch word (all
        // lanes same address -> one broadcast transaction per round).
        VMWAIT(0);
        __syncthreads();
        {
            const unsigned tgt = (unsigned)(p + 1);
            if (wave == 0 && lane == 0) GSTOREU32(flags + blockIdx.x, tgt);

            // X(t+1) prefetch AFTER the release post: HBM latency overlaps
            // the barrier wait instead of delaying it. (t == p for layer 0.)
            if (layer == 0 && t + 1 < S_) {
                const float* xp = Xin + ((size_t)arow * S_ + (t + 1)) * 512 + (quad << 3);
                #pragma unroll
                for (int kk = 0; kk < 16; ++kk) {
                    float4 f0 = *(const float4*)(xp + kk * 32);
                    float4 f1 = *(const float4*)(xp + kk * 32 + 4);
                    xa[kk] = pack8(f0, f1);
                }
            }

            if (wave == 0) {
                if (blockIdx.x == 0) {
                    const unsigned* fp = flags + lane;
                    unsigned v;
                    do { GLOADU32(v, fp); } while (__any(v < tgt));
                    if (lane == 0) GSTOREU32(flags + 128, tgt);   // publish epoch
                } else {
                    unsigned v;
                    do { GLOADU32(v, flags + 128); } while (v < tgt);
                }
            }
            __syncthreads();
        }
    }

    {
        v4f hv = {hreg[0], hreg[1], hreg[2], hreg[3]};
        *(v4f*)(hfin + (size_t)layer * (B_ * H_) + arow * 512 + ncol) = hv;
    }
}

extern "C" void kernel_launch(void* const* d_in, const int* in_sizes, int n_in,
                              void* d_out, int out_size, void* d_ws, size_t ws_size,
                              hipStream_t stream)
{
    const float* x  = (const float*)d_in[0];
    const float* Wg = (const float*)d_in[1];
    const float* bg = (const float*)d_in[2];
    const float* Wi = (const float*)d_in[3];
    const float* bi = (const float*)d_in[4];
    const float* Wh = (const float*)d_in[5];

    float* out = (float*)d_out;                       // (B,S,H)
    float* hid = out + (size_t)B_ * S_ * H_;          // (L,B,H)

    // ws layout (bytes): [h0 frag-order dbuf: 128KB][h1: 128KB][flags+epoch: 4KB]
    unsigned short* h0b = (unsigned short*)d_ws;
    unsigned short* h1b = h0b + 2 * BH;                                  // +128KB
    unsigned int*   flg = (unsigned int*)((char*)d_ws + (size_t)8 * BH); // byte 262144

    hipMemsetAsync(d_ws, 0, (size_t)8 * BH + 4096, stream);   // h state + flags + epoch

    gru_fused<<<dim3(NWG), dim3(256), 0, stream>>>(
        x, Wg, bg, Wi, bi, Wh, out, hid, h0b, h1b, flg);
}